// Round 10
// baseline (98.596 us; speedup 1.0000x reference)
//
#include <hip/hip_runtime.h>
#include <math.h>

#define EPSF 1e-5f

__device__ __forceinline__ float sigm(float v){ return 1.f/(1.f+__expf(-v)); }

// ---------------------------------------------------------------------------
// ws layout (floats)
// ---------------------------------------------------------------------------
#define WS_H    0
#define WS_Q    100864
#define WS_K    201728
#define WS_V    302592
#define WS_G    403456
#define WS_AO   409760
#define WS_PWT  510624
#define WS_WQT  608928
#define WS_WKT  641696
#define WS_WVT  674464
#define WS_WOT  707232
#define WS_GWT  740000
#define WS_TUT  742048
#define WS_CUT  807584
#define WS_FGT  873120
#define WS_DNT  938656
#define WS_HDT  1004192

// ---------------------------------------------------------------------------
// K0: LDS-tiled weight transpose (unchanged from R9)
// ---------------------------------------------------------------------------
__global__ __launch_bounds__(256) void k_tr(
    const float* __restrict__ pw, const float* __restrict__ wq, const float* __restrict__ wk,
    const float* __restrict__ wv, const float* __restrict__ wo, const float* __restrict__ gw,
    const float* __restrict__ tu, const float* __restrict__ cu, const float* __restrict__ fg,
    const float* __restrict__ dn, const float* __restrict__ hd, float* __restrict__ ws)
{
    __shared__ float tile[32][33];
    int tn = blockIdx.x, t = threadIdx.x;

    if (tn >= 608) {
        for (int i=t;i<2048;i+=256){
            int m=i>>10, rem=i&1023, k=rem>>3, hh=rem&7;
            ws[WS_GWT + m*1024 + k*8 + hh] = gw[m*1024 + hh*128 + k];
        }
        return;
    }

    const float* srcp; long dstoff; int N, K, NR, nt, kt;
    if (tn < 96) {
        srcp=pw; dstoff=WS_PWT; N=128; K=768; NR=128; nt=tn/24; kt=tn%24;
    } else if (tn < 224) {
        int i2=tn-96, inst=i2>>4, lt=i2&15, m2=inst>>1;
        srcp = (m2==0)?wq:(m2==1)?wk:(m2==2)?wv:wo;
        srcp += (inst&1)*16384;
        dstoff = WS_WQT + (long)m2*32768 + (inst&1)*16384;
        N=128; K=128; NR=128; nt=lt>>2; kt=lt&3;
    } else if (tn < 416) {
        int i2=tn-224, inst=i2>>5, lt=i2&31, m2=inst>>1;
        srcp = (m2==0)?tu:(m2==1)?cu:fg;
        srcp += (inst&1)*32768;
        dstoff = WS_TUT + (long)m2*65536 + (inst&1)*32768;
        N=256; K=128; NR=256; nt=lt>>2; kt=lt&3;
    } else if (tn < 480) {
        int i2=tn-416, inst=i2>>5, lt=i2&31;
        srcp = dn + inst*32768; dstoff = WS_DNT + (long)inst*32768;
        N=128; K=256; NR=128; nt=lt>>3; kt=lt&7;
    } else {
        int lt=tn-480; srcp=hd; dstoff=WS_HDT; N=1000; K=128; NR=1000; nt=lt>>2; kt=lt&3;
    }

    int n0=nt*32, k0=kt*32;
    int tr=t>>3, tc=(t&7)*4;
    float4 v={0.f,0.f,0.f,0.f};
    if (n0+tr < NR) v = *(const float4*)(srcp + (size_t)(n0+tr)*K + k0 + tc);
    tile[tr][tc]=v.x; tile[tr][tc+1]=v.y; tile[tr][tc+2]=v.z; tile[tr][tc+3]=v.w;
    __syncthreads();
    int kr=t>>3, nc=(t&7)*4;
    float o0=tile[nc][kr], o1=tile[nc+1][kr], o2=tile[nc+2][kr], o3=tile[nc+3][kr];
    float* dp = ws + dstoff + (size_t)(k0+kr)*N + n0 + nc;
    if (n0+nc+3 < NR) {
        float4 o4={o0,o1,o2,o3};
        *(float4*)dp = o4;
    } else {
        if (n0+nc   < NR) dp[0]=o0;
        if (n0+nc+1 < NR) dp[1]=o1;
        if (n0+nc+2 < NR) dp[2]=o2;
        if (n0+nc+3 < NR) dp[3]=o3;
    }
}

// Distributed LayerNorm over 8 rows: thread handles slots t and t+512.
__device__ __forceinline__ void ln8(const float hv[2],
    const float* __restrict__ lw, const float* __restrict__ lb,
    float* hnS, float* redS, float* redS2, int t)
{
    #pragma unroll
    for (int s=0;s<2;++s){
        float sm=hv[s], sq=hv[s]*hv[s];
        #pragma unroll
        for (int o=1;o<64;o<<=1){ sm+=__shfl_xor(sm,o); sq+=__shfl_xor(sq,o); }
        if ((t&63)==0){
            int slot=t+s*512, r=slot>>7, half=(t>>6)&1;
            redS[r*2+half]=sm; redS2[r*2+half]=sq;
        }
    }
    __syncthreads();
    #pragma unroll
    for (int s=0;s<2;++s){
        int slot=t+s*512, r=slot>>7, d=slot&127;
        float S=redS[r*2]+redS[r*2+1], S2=redS2[r*2]+redS2[r*2+1];
        float mu=S*(1.f/128.f), var=S2*(1.f/128.f)-mu*mu;
        float rr=rsqrtf(var+EPSF);
        hnS[r*128+d]=(hv[s]-mu)*rr*lw[d]+lb[d];
    }
    __syncthreads();
}

// QKV + gate for 8 rows from hnS.  uni = 16384-float scratch (pacc).
// Tropical partials (Q,K) combine with MAX; classical (V) with SUM.
__device__ __forceinline__ void qkvT8(const float* hnS, float* uni, int r0, int t,
    const float* __restrict__ wqT, const float* __restrict__ bq,
    const float* __restrict__ wkT, const float* __restrict__ bk,
    const float* __restrict__ wvT, const float* __restrict__ bv,
    const float* __restrict__ gwT, const float* __restrict__ gb,
    float* __restrict__ Q, float* __restrict__ Kg, float* __restrict__ V,
    float* __restrict__ g)
{
    if (t < 384) {
        int mat = t >> 7, q4i = t & 31, ks = (t >> 5) & 3;
        const float* wT = (mat==0) ? wqT : (mat==1) ? wkT : wvT;
        const float4* w4 = (const float4*)wT + q4i;
        float4 acc[8];
        if (mat < 2) {
            #pragma unroll
            for (int r=0;r<8;++r){ acc[r].x=acc[r].y=acc[r].z=acc[r].w=-1e30f; }
            #pragma unroll
            for (int kb=0;kb<4;++kb){
                float4 wv8[8];
                #pragma unroll
                for (int j=0;j<8;++j) wv8[j]=w4[(ks*32+kb*8+j)*32];
                #pragma unroll
                for (int j=0;j<8;++j){
                    float4 w=wv8[j];
                    #pragma unroll
                    for (int r=0;r<8;++r){
                        float av = hnS[r*128 + ks*32+kb*8+j];
                        acc[r].x=fmaxf(acc[r].x,av+w.x); acc[r].y=fmaxf(acc[r].y,av+w.y);
                        acc[r].z=fmaxf(acc[r].z,av+w.z); acc[r].w=fmaxf(acc[r].w,av+w.w);
                    }
                }
            }
        } else {
            #pragma unroll
            for (int r=0;r<8;++r){ acc[r].x=acc[r].y=acc[r].z=acc[r].w=0.f; }
            #pragma unroll
            for (int kb=0;kb<4;++kb){
                float4 wv8[8];
                #pragma unroll
                for (int j=0;j<8;++j) wv8[j]=w4[(ks*32+kb*8+j)*32];
                #pragma unroll
                for (int j=0;j<8;++j){
                    float4 w=wv8[j];
                    #pragma unroll
                    for (int r=0;r<8;++r){
                        float av = hnS[r*128 + ks*32+kb*8+j];
                        acc[r].x=fmaf(av,w.x,acc[r].x); acc[r].y=fmaf(av,w.y,acc[r].y);
                        acc[r].z=fmaf(av,w.z,acc[r].z); acc[r].w=fmaf(av,w.w,acc[r].w);
                    }
                }
            }
        }
        #pragma unroll
        for (int r=0;r<8;++r)
            *(float4*)(uni + mat*4096 + ks*1024 + r*128 + q4i*4) = acc[r];
    } else {
        int u = t & 127, r8 = u>>4, hh=(u>>1)&7, ks2=u&1;
        const float* a = hnS + r8*128;
        float acc = 0.f;
        #pragma unroll
        for (int kb=0;kb<8;++kb){
            float wv8[8];
            #pragma unroll
            for (int j=0;j<8;++j) wv8[j]=gwT[(ks2*64+kb*8+j)*8+hh];
            #pragma unroll
            for (int j=0;j<8;++j) acc = fmaf(a[ks2*64+kb*8+j], wv8[j], acc);
        }
        acc += __shfl_xor(acc,1);
        int row=r0+r8;
        if (ks2==0 && row<788) g[row*8+hh] = sigm(acc + gb[hh]);
    }
    __syncthreads();
    if (t < 384) {
        int mat=t>>7, d=t&127;
        float* dst = (mat==0) ? Q : (mat==1) ? Kg : V;
        const float* bias = (mat==0) ? bq : (mat==1) ? bk : bv;
        #pragma unroll
        for (int r=0;r<8;++r){
            float p0 = uni[mat*4096 + 0*1024 + r*128 + d];
            float p1 = uni[mat*4096 + 1*1024 + r*128 + d];
            float p2 = uni[mat*4096 + 2*1024 + r*128 + d];
            float p3 = uni[mat*4096 + 3*1024 + r*128 + d];
            float s = (mat < 2) ? fmaxf(fmaxf(p0,p1), fmaxf(p2,p3))
                                : (p0 + p1 + p2 + p3);
            int row=r0+r;
            if (row<788) dst[(size_t)row*128 + d] = s + bias[d];
        }
    }
}

// ---------------------------------------------------------------------------
// K1: patchify + patch embed + BN + LN1 + QKVG(layer0).  99 blocks x 512, 8 rows
// ---------------------------------------------------------------------------
__global__ __launch_bounds__(512) void k_p1(
    const float* __restrict__ x, const float* __restrict__ pwT, const float* __restrict__ pb,
    const float* __restrict__ clsT, const float* __restrict__ pos,
    const float* __restrict__ bng, const float* __restrict__ bnb,
    const float* __restrict__ bnm, const float* __restrict__ bnr,
    const float* __restrict__ n1w, const float* __restrict__ n1b,
    const float* __restrict__ wqT, const float* __restrict__ bq,
    const float* __restrict__ wkT, const float* __restrict__ bk,
    const float* __restrict__ wvT, const float* __restrict__ bv,
    const float* __restrict__ gwT, const float* __restrict__ gb,
    float* __restrict__ h, float* __restrict__ Q, float* __restrict__ Kg,
    float* __restrict__ V, float* __restrict__ g)
{
    __shared__ __align__(16) float xp[8*768];
    __shared__ __align__(16) float uni[16384];
    __shared__ __align__(16) float hnS[1024];
    __shared__ float redS[16], redS2[16];
    int t = threadIdx.x, r0 = blockIdx.x * 8;

    // stage 8 patches
    #pragma unroll
    for (int r=0;r<8;++r){
        int row=r0+r;
        if (row < 788){
            int b=row/197, l=row-b*197;
            if (l>0){
                int patch=l-1, ph=patch/14, pc=patch-ph*14;
                const float* xb = x + (size_t)b*150528 + ph*3584 + pc*16;
                for (int i=t;i<768;i+=512){
                    int c=i>>8, rr=(i>>4)&15, cc=i&15;
                    xp[r*768+i] = xb[c*50176 + rr*224 + cc];
                }
            }
        }
    }
    __syncthreads();

    // patch GEMM: 32 q4i x 16 ks (48 k each), 6 rounds of batch-8
    {
        int q4i = t & 31, ks = t >> 5;
        float4 acc[8];
        #pragma unroll
        for (int r=0;r<8;++r){ acc[r].x=acc[r].y=acc[r].z=acc[r].w=0.f; }
        const float4* w4 = (const float4*)pwT + q4i;
        #pragma unroll
        for (int kb=0;kb<6;++kb){
            float4 wv8[8];
            #pragma unroll
            for (int j=0;j<8;++j) wv8[j]=w4[(ks*48+kb*8+j)*32];
            #pragma unroll
            for (int j=0;j<8;++j){
                float4 w=wv8[j];
                #pragma unroll
                for (int r=0;r<8;++r){
                    float av = xp[r*768 + ks*48+kb*8+j];
                    acc[r].x=fmaf(av,w.x,acc[r].x); acc[r].y=fmaf(av,w.y,acc[r].y);
                    acc[r].z=fmaf(av,w.z,acc[r].z); acc[r].w=fmaf(av,w.w,acc[r].w);
                }
            }
        }
        #pragma unroll
        for (int r=0;r<8;++r)
            *(float4*)(uni + (ks*8+r)*128 + q4i*4) = acc[r];
    }
    __syncthreads();

    float hres[2];
    #pragma unroll
    for (int s=0;s<2;++s){
        int slot=t+s*512, r=slot>>7, d=slot&127;
        int row=r0+r, l=row%197;
        float sm = 0.f;
        #pragma unroll
        for (int ks=0;ks<16;++ks) sm += uni[(ks*8+r)*128+d];
        float v = (l==0) ? clsT[d] : (sm + pb[d]);
        v += pos[l*128+d];
        v = bng[d]*((v-bnm[d])/(bnr[d]+EPSF))+bnb[d];
        hres[s]=v;
        if (row<788) h[(size_t)row*128+d]=v;
    }
    __syncthreads();
    ln8(hres, n1w, n1b, hnS, redS, redS2, t);
    qkvT8(hnS, uni, r0, t, wqT,bq,wkT,bk,wvT,bv,gwT,gb, Q,Kg,V,g);
}

// ---------------------------------------------------------------------------
// K2: fused attention (unchanged).  224 blocks x 256
// ---------------------------------------------------------------------------
__global__ __launch_bounds__(256) void k_attn(
    const float* __restrict__ Qd, const float* __restrict__ Kd,
    const float* __restrict__ Vd, const float* __restrict__ gd,
    const float* __restrict__ tempL, float* __restrict__ ao)
{
    __shared__ __align__(16) float Ks[197*20];
    __shared__ __align__(16) float Vs[197*20];
    int bid = blockIdx.x, t = threadIdx.x;
    int qc = bid % 7, bh = bid / 7, hh = bh & 7, b = bh >> 3;
    size_t base = (size_t)(b*197)*128 + hh*16;

    {
        const float4* ksrc=(const float4*)(Kd+base);
        const float4* vsrc=(const float4*)(Vd+base);
        float4* kdst=(float4*)Ks; float4* vdst=(float4*)Vs;
        for (int idx=t; idx<788; idx+=256){
            int l=idx>>2, jj=idx&3;
            kdst[l*5+jj]=ksrc[l*32+jj];
            vdst[l*5+jj]=vsrc[l*32+jj];
        }
    }
    __syncthreads();

    int q = qc*32 + (t>>3), j8 = t&7;
    if (q >= 197) return;

    float Qr[16];
    {
        const float4* qp=(const float4*)(Qd+base+(size_t)q*128);
        #pragma unroll
        for (int u=0;u<4;++u){
            float4 v=qp[u];
            Qr[4*u]=v.x; Qr[4*u+1]=v.y; Qr[4*u+2]=v.z; Qr[4*u+3]=v.w;
        }
    }
    float gq = gd[(b*197+q)*8+hh];
    float it = 0.25f / tempL[hh];
    float gg = gq*it, cg = (1.f-gq)*it;

    float m=-1e30f, lsum=0.f, o[16];
    #pragma unroll
    for (int j=0;j<16;++j) o[j]=0.f;

    for (int k=j8;k<197;k+=8){
        const float4* kr4=(const float4*)(Ks+k*20);
        float4 kv0=kr4[0], kv1=kr4[1], kv2=kr4[2], kv3=kr4[3];
        float kr[16] = {kv0.x,kv0.y,kv0.z,kv0.w, kv1.x,kv1.y,kv1.z,kv1.w,
                        kv2.x,kv2.y,kv2.z,kv2.w, kv3.x,kv3.y,kv3.z,kv3.w};
        float cs=0.f, ts=-1e30f;
        #pragma unroll
        for (int j=0;j<16;++j){
            cs=fmaf(Qr[j],kr[j],cs);
            ts=fmaxf(ts,Qr[j]+kr[j]);
        }
        float sc=fmaf(gg,ts,cg*cs);
        if (sc>m){
            float c=__expf(m-sc);
            lsum*=c;
            #pragma unroll
            for (int j=0;j<16;++j) o[j]*=c;
            m=sc;
        }
        float p=__expf(sc-m);
        lsum+=p;
        const float4* vr4=(const float4*)(Vs+k*20);
        float4 vv0=vr4[0], vv1=vr4[1], vv2=vr4[2], vv3=vr4[3];
        float vr[16] = {vv0.x,vv0.y,vv0.z,vv0.w, vv1.x,vv1.y,vv1.z,vv1.w,
                        vv2.x,vv2.y,vv2.z,vv2.w, vv3.x,vv3.y,vv3.z,vv3.w};
        #pragma unroll
        for (int j=0;j<16;++j) o[j]=fmaf(p,vr[j],o[j]);
    }

    #pragma unroll
    for (int mask=1;mask<8;mask<<=1){
        float mo=__shfl_xor(m,mask), lo=__shfl_xor(lsum,mask);
        float mn=fmaxf(m,mo);
        float ea=__expf(m-mn), eb=__expf(mo-mn);
        lsum=lsum*ea+lo*eb;
        #pragma unroll
        for (int j=0;j<16;++j){
            float oo=__shfl_xor(o[j],mask);
            o[j]=o[j]*ea+oo*eb;
        }
        m=mn;
    }

    if (j8==0){
        float inv=1.f/lsum;
        float* orow=ao+base+(size_t)q*128;
        #pragma unroll
        for (int j=0;j<16;++j) orow[j]=o[j]*inv;
    }
}

// ---------------------------------------------------------------------------
// K3: oproj+res+LN2 + FFN + dproj+res + next-LN + (QKVG | head)
// 99 blocks x 512, 8 rows/block.
// ---------------------------------------------------------------------------
template <int FINAL>
__global__ __launch_bounds__(512) void k_p34(
    const float* __restrict__ ao, float* __restrict__ h,
    const float* __restrict__ woT, const float* __restrict__ bo,
    const float* __restrict__ n2w, const float* __restrict__ n2b,
    const float* __restrict__ tuT, const float* __restrict__ tub,
    const float* __restrict__ laA, const float* __restrict__ laC,
    const float* __restrict__ lgG,
    const float* __restrict__ cuT, const float* __restrict__ cub,
    const float* __restrict__ fgT, const float* __restrict__ fgb,
    const float* __restrict__ dnT, const float* __restrict__ dnb,
    const float* __restrict__ nlw, const float* __restrict__ nlb,
    const float* __restrict__ wqT, const float* __restrict__ bq,
    const float* __restrict__ wkT, const float* __restrict__ bk,
    const float* __restrict__ wvT, const float* __restrict__ bv,
    const float* __restrict__ gwT, const float* __restrict__ gb,
    float* __restrict__ Q, float* __restrict__ Kg, float* __restrict__ V,
    float* __restrict__ g,
    const float* __restrict__ hdT, const float* __restrict__ hdb,
    float* __restrict__ out)
{
    __shared__ __align__(16) float aoS[1024];
    __shared__ __align__(16) float uni[16384];
    __shared__ __align__(16) float hnS[1024];
    __shared__ __align__(16) float fusedS[2048];
    __shared__ float redS[16], redS2[16];
    int t = threadIdx.x, r0 = blockIdx.x * 8;

    aoS[t]     = ao[(size_t)r0*128 + t];
    aoS[t+512] = ao[(size_t)r0*128 + t + 512];
    __syncthreads();

    // oproj: 32 q4i x 16 ks (8 k each), one batch-8 round
    {
        int q4i=t&31, ks=t>>5;
        float4 acc[8];
        #pragma unroll
        for (int r=0;r<8;++r){ acc[r].x=acc[r].y=acc[r].z=acc[r].w=0.f; }
        const float4* w4=(const float4*)woT + q4i;
        float4 wv8[8];
        #pragma unroll
        for (int j=0;j<8;++j) wv8[j]=w4[(ks*8+j)*32];
        #pragma unroll
        for (int j=0;j<8;++j){
            float4 w=wv8[j];
            #pragma unroll
            for (int r=0;r<8;++r){
                float av=aoS[r*128 + ks*8+j];
                acc[r].x=fmaf(av,w.x,acc[r].x); acc[r].y=fmaf(av,w.y,acc[r].y);
                acc[r].z=fmaf(av,w.z,acc[r].z); acc[r].w=fmaf(av,w.w,acc[r].w);
            }
        }
        #pragma unroll
        for (int r=0;r<8;++r)
            *(float4*)(uni + (ks*8+r)*128 + q4i*4) = acc[r];
    }
    __syncthreads();

    float hres[2];
    #pragma unroll
    for (int s=0;s<2;++s){
        int slot=t+s*512, r=slot>>7, d=slot&127;
        float sm=0.f;
        #pragma unroll
        for (int ks=0;ks<16;++ks) sm += uni[(ks*8+r)*128+d];
        hres[s] = h[(size_t)(r0+r)*128+d] + sm + bo[d];
    }
    __syncthreads();
    ln8(hres, n2w, n2b, hnS, redS, redS2, t);

    // FFN: 6 groups of 64 = (mat 0..2) x (k-half 0..1), 8 rounds batch-8
    {
        int gidx=t>>6, fq=t&63;
        if (gidx < 6) {
            int mat=gidx>>1, ks2=gidx&1;
            const float* wT = (mat==0)? tuT : (mat==1)? cuT : fgT;
            const float4* w4=(const float4*)wT + fq;
            float4 acc[8];
            if (mat==0){
                #pragma unroll
                for (int r=0;r<8;++r){ acc[r].x=acc[r].y=acc[r].z=acc[r].w=-1e30f; }
                #pragma unroll
                for (int kb=0;kb<8;++kb){
                    float4 wv8[8];
                    #pragma unroll
                    for (int j=0;j<8;++j) wv8[j]=w4[(ks2*64+kb*8+j)*64];
                    #pragma unroll
                    for (int j=0;j<8;++j){
                        float4 w=wv8[j];
                        #pragma unroll
                        for (int r=0;r<8;++r){
                            float av=hnS[r*128 + ks2*64+kb*8+j];
                            acc[r].x=fmaxf(acc[r].x,av+w.x); acc[r].y=fmaxf(acc[r].y,av+w.y);
                            acc[r].z=fmaxf(acc[r].z,av+w.z); acc[r].w=fmaxf(acc[r].w,av+w.w);
                        }
                    }
                }
            } else {
                #pragma unroll
                for (int r=0;r<8;++r){ acc[r].x=acc[r].y=acc[r].z=acc[r].w=0.f; }
                #pragma unroll
                for (int kb=0;kb<8;++kb){
                    float4 wv8[8];
                    #pragma unroll
                    for (int j=0;j<8;++j) wv8[j]=w4[(ks2*64+kb*8+j)*64];
                    #pragma unroll
                    for (int j=0;j<8;++j){
                        float4 w=wv8[j];
                        #pragma unroll
                        for (int r=0;r<8;++r){
                            float av=hnS[r*128 + ks2*64+kb*8+j];
                            acc[r].x=fmaf(av,w.x,acc[r].x); acc[r].y=fmaf(av,w.y,acc[r].y);
                            acc[r].z=fmaf(av,w.z,acc[r].z); acc[r].w=fmaf(av,w.w,acc[r].w);
                        }
                    }
                }
            }
            #pragma unroll
            for (int r=0;r<8;++r)
                *(float4*)(uni + mat*4096 + ks2*2048 + r*256 + fq*4) = acc[r];
        }
    }
    __syncthreads();

    // FFN epilogue: 2048 (r,f) slots over 512 threads (4 each)
    #pragma unroll
    for (int s2=0;s2<4;++s2){
        int slot = t + s2*512;
        int r = slot>>8, f = slot&255;
        float z  = fmaxf(uni[r*256+f],          uni[2048+r*256+f]) + tub[f];
        float xc = uni[4096+r*256+f]  + uni[4096+2048+r*256+f]  + cub[f];
        float gv = uni[8192+r*256+f]  + uni[8192+2048+r*256+f]  + fgb[f];
        float gl = sigm(lgG[f]);
        float mx=-1e30f, mn=1e30f;
        #pragma unroll
        for (int p=0;p<8;++p){
            float zp=fmaf(z, laA[p*256+f], laC[p*256+f]);
            mx=fmaxf(mx,zp); mn=fminf(mn,zp);
        }
        float trop=gl*mx+(1.f-gl)*mn;
        float cla=0.5f*xc*(1.f+erff(xc*0.70710678118654752f));
        float gf=sigm(gv);
        fusedS[r*256+f]=gf*trop+(1.f-gf)*cla;
    }
    __syncthreads();

    // dproj: 32 q4i x 16 ks (16 k each of 256), 2 rounds batch-8
    {
        int q4i=t&31, ks=t>>5;
        float4 acc[8];
        #pragma unroll
        for (int r=0;r<8;++r){ acc[r].x=acc[r].y=acc[r].z=acc[r].w=0.f; }
        const float4* w4=(const float4*)dnT + q4i;
        #pragma unroll
        for (int kb=0;kb<2;++kb){
            float4 wv8[8];
            #pragma unroll
            for (int j=0;j<8;++j) wv8[j]=w4[(ks*16+kb*8+j)*32];
            #pragma unroll
            for (int j=0;j<8;++j){
                float4 w=wv8[j];
                #pragma unroll
                for (int r=0;r<8;++r){
                    float av=fusedS[r*256 + ks*16+kb*8+j];
                    acc[r].x=fmaf(av,w.x,acc[r].x); acc[r].y=fmaf(av,w.y,acc[r].y);
                    acc[r].z=fmaf(av,w.z,acc[r].z); acc[r].w=fmaf(av,w.w,acc[r].w);
                }
            }
        }
        __syncthreads();
        #pragma unroll
        for (int r=0;r<8;++r)
            *(float4*)(uni + (ks*8+r)*128 + q4i*4) = acc[r];
    }
    __syncthreads();
    #pragma unroll
    for (int s=0;s<2;++s){
        int slot=t+s*512, r=slot>>7, d=slot&127;
        float sm=0.f;
        #pragma unroll
        for (int ks=0;ks<16;++ks) sm += uni[(ks*8+r)*128+d];
        hres[s] += sm + dnb[d];
        int row=r0+r;
        if (!FINAL && row<788) h[(size_t)row*128+d]=hres[s];
    }
    __syncthreads();
    ln8(hres, nlw, nlb, hnS, redS, redS2, t);

    if (!FINAL) {
        qkvT8(hnS, uni, r0, t, wqT,bq,wkT,bk,wvT,bv,gwT,gb, Q,Kg,V,g);
    } else {
        int crow=-1, cb2=0;
        #pragma unroll
        for (int r=0;r<8;++r){
            int row=r0+r;
            if (row<788 && row%197==0){ crow=r; cb2=row/197; }
        }
        if (crow>=0 && t<500){
            const float2* w2=(const float2*)hdT + t;
            const float* a = hnS + crow*128;
            float acc0=hdb[2*t], acc1=hdb[2*t+1];
            #pragma unroll
            for (int kb=0;kb<16;++kb){
                float2 wv8[8];
                #pragma unroll
                for (int j=0;j<8;++j) wv8[j]=w2[(kb*8+j)*500];
                #pragma unroll
                for (int j=0;j<8;++j){
                    float av=a[kb*8+j];
                    acc0=fmaf(av,wv8[j].x,acc0); acc1=fmaf(av,wv8[j].y,acc1);
                }
            }
            out[cb2*1000+2*t]=acc0;
            out[cb2*1000+2*t+1]=acc1;
        }
    }
}

// ---------------------------------------------------------------------------
extern "C" void kernel_launch(void* const* d_in, const int* in_sizes, int n_in,
                              void* d_out, int out_size, void* d_ws, size_t ws_size,
                              hipStream_t stream)
{
    const float* x        = (const float*)d_in[0];
    const float* patch_w  = (const float*)d_in[1];
    const float* patch_b  = (const float*)d_in[2];
    const float* cls_tok  = (const float*)d_in[3];
    const float* pos_emb  = (const float*)d_in[4];
    const float* bn_gamma = (const float*)d_in[5];
    const float* bn_beta  = (const float*)d_in[6];
    const float* bn_rmax  = (const float*)d_in[7];
    const float* bn_rrng  = (const float*)d_in[8];
    const float* n1_w     = (const float*)d_in[9];
    const float* n1_b     = (const float*)d_in[10];
    const float* n2_w     = (const float*)d_in[11];
    const float* n2_b     = (const float*)d_in[12];
    const float* wq       = (const float*)d_in[13];
    const float* bq       = (const float*)d_in[14];
    const float* wk       = (const float*)d_in[15];
    const float* bk       = (const float*)d_in[16];
    const float* wv       = (const float*)d_in[17];
    const float* bv       = (const float*)d_in[18];
    const float* wo       = (const float*)d_in[19];
    const float* bo       = (const float*)d_in[20];
    const float* gate_w   = (const float*)d_in[21];
    const float* gate_b   = (const float*)d_in[22];
    const float* temp     = (const float*)d_in[23];
    const float* tu_w     = (const float*)d_in[24];
    const float* tu_b     = (const float*)d_in[25];
    const float* lf_a     = (const float*)d_in[26];
    const float* lf_c     = (const float*)d_in[27];
    const float* lf_gate  = (const float*)d_in[28];
    const float* cu_w     = (const float*)d_in[29];
    const float* cu_b     = (const float*)d_in[30];
    const float* fg_w     = (const float*)d_in[31];
    const float* fg_b     = (const float*)d_in[32];
    const float* dn_w     = (const float*)d_in[33];
    const float* dn_b     = (const float*)d_in[34];
    const float* fn_w     = (const float*)d_in[35];
    const float* fn_b     = (const float*)d_in[36];
    const float* head_w   = (const float*)d_in[37];
    const float* head_b   = (const float*)d_in[38];

    float* ws = (float*)d_ws;
    float* h   = ws + WS_H;
    float* Q   = ws + WS_Q;
    float* Kb  = ws + WS_K;
    float* V   = ws + WS_V;
    float* g   = ws + WS_G;
    float* ao  = ws + WS_AO;
    float* out = (float*)d_out;

    k_tr<<<609, 256, 0, stream>>>(patch_w, wq, wk, wv, wo, gate_w,
                                  tu_w, cu_w, fg_w, dn_w, head_w, ws);

    k_p1<<<99, 512, 0, stream>>>(x, ws+WS_PWT, patch_b, cls_tok, pos_emb,
                                 bn_gamma, bn_beta, bn_rmax, bn_rrng,
                                 n1_w, n1_b,
                                 ws+WS_WQT, bq, ws+WS_WKT, bk, ws+WS_WVT, bv,
                                 ws+WS_GWT, gate_b,
                                 h, Q, Kb, V, g);

    k_attn<<<224, 256, 0, stream>>>(Q, Kb, V, g, temp, ao);

    k_p34<0><<<99, 512, 0, stream>>>(ao, h,
        ws+WS_WOT, bo, n2_w, n2_b,
        ws+WS_TUT, tu_b, lf_a, lf_c, lf_gate,
        ws+WS_CUT, cu_b, ws+WS_FGT, fg_b, ws+WS_DNT, dn_b,
        n1_w + 128, n1_b + 128,
        ws+WS_WQT+16384, bq + 128, ws+WS_WKT+16384, bk + 128,
        ws+WS_WVT+16384, bv + 128, ws+WS_GWT+1024, gate_b + 8,
        Q, Kb, V, g, nullptr, nullptr, nullptr);

    k_attn<<<224, 256, 0, stream>>>(Q, Kb, V, g, temp + 8, ao);

    k_p34<1><<<99, 512, 0, stream>>>(ao, h,
        ws+WS_WOT+16384, bo + 128, n2_w + 128, n2_b + 128,
        ws+WS_TUT+32768, tu_b + 256, lf_a + 2048, lf_c + 2048, lf_gate + 256,
        ws+WS_CUT+32768, cu_b + 256, ws+WS_FGT+32768, fg_b + 256,
        ws+WS_DNT+32768, dn_b + 128,
        fn_w, fn_b,
        nullptr, nullptr, nullptr, nullptr, nullptr, nullptr, nullptr, nullptr,
        Q, Kb, V, g, ws+WS_HDT, head_b, out);
}

// Round 12
// 76.826 us; speedup vs baseline: 1.2834x; 1.2834x over previous
//
#include <hip/hip_runtime.h>
#include <math.h>

#define EPSF 1e-5f

__device__ __forceinline__ float sigm(float v){ return 1.f/(1.f+__expf(-v)); }

// ---------------------------------------------------------------------------
// ws layout (floats)
// ---------------------------------------------------------------------------
#define WS_H    0
#define WS_Q    100864
#define WS_K    201728
#define WS_V    302592
#define WS_G    403456
#define WS_AO   409760
#define WS_PWT  510624
#define WS_WQT  608928
#define WS_WKT  641696
#define WS_WVT  674464
#define WS_WOT  707232
#define WS_GWT  740000
#define WS_TUT  742048
#define WS_CUT  807584
#define WS_FGT  873120
#define WS_DNT  938656
#define WS_HDT  1004192

// ---------------------------------------------------------------------------
// K0: LDS-tiled weight transpose (unchanged)
// ---------------------------------------------------------------------------
__global__ __launch_bounds__(256) void k_tr(
    const float* __restrict__ pw, const float* __restrict__ wq, const float* __restrict__ wk,
    const float* __restrict__ wv, const float* __restrict__ wo, const float* __restrict__ gw,
    const float* __restrict__ tu, const float* __restrict__ cu, const float* __restrict__ fg,
    const float* __restrict__ dn, const float* __restrict__ hd, float* __restrict__ ws)
{
    __shared__ float tile[32][33];
    int tn = blockIdx.x, t = threadIdx.x;

    if (tn >= 608) {
        for (int i=t;i<2048;i+=256){
            int m=i>>10, rem=i&1023, k=rem>>3, hh=rem&7;
            ws[WS_GWT + m*1024 + k*8 + hh] = gw[m*1024 + hh*128 + k];
        }
        return;
    }

    const float* srcp; long dstoff; int N, K, NR, nt, kt;
    if (tn < 96) {
        srcp=pw; dstoff=WS_PWT; N=128; K=768; NR=128; nt=tn/24; kt=tn%24;
    } else if (tn < 224) {
        int i2=tn-96, inst=i2>>4, lt=i2&15, m2=inst>>1;
        srcp = (m2==0)?wq:(m2==1)?wk:(m2==2)?wv:wo;
        srcp += (inst&1)*16384;
        dstoff = WS_WQT + (long)m2*32768 + (inst&1)*16384;
        N=128; K=128; NR=128; nt=lt>>2; kt=lt&3;
    } else if (tn < 416) {
        int i2=tn-224, inst=i2>>5, lt=i2&31, m2=inst>>1;
        srcp = (m2==0)?tu:(m2==1)?cu:fg;
        srcp += (inst&1)*32768;
        dstoff = WS_TUT + (long)m2*65536 + (inst&1)*32768;
        N=256; K=128; NR=256; nt=lt>>2; kt=lt&3;
    } else if (tn < 480) {
        int i2=tn-416, inst=i2>>5, lt=i2&31;
        srcp = dn + inst*32768; dstoff = WS_DNT + (long)inst*32768;
        N=128; K=256; NR=128; nt=lt>>3; kt=lt&7;
    } else {
        int lt=tn-480; srcp=hd; dstoff=WS_HDT; N=1000; K=128; NR=1000; nt=lt>>2; kt=lt&3;
    }

    int n0=nt*32, k0=kt*32;
    int tr=t>>3, tc=(t&7)*4;
    float4 v={0.f,0.f,0.f,0.f};
    if (n0+tr < NR) v = *(const float4*)(srcp + (size_t)(n0+tr)*K + k0 + tc);
    tile[tr][tc]=v.x; tile[tr][tc+1]=v.y; tile[tr][tc+2]=v.z; tile[tr][tc+3]=v.w;
    __syncthreads();
    int kr=t>>3, nc=(t&7)*4;
    float o0=tile[nc][kr], o1=tile[nc+1][kr], o2=tile[nc+2][kr], o3=tile[nc+3][kr];
    float* dp = ws + dstoff + (size_t)(k0+kr)*N + n0 + nc;
    if (n0+nc+3 < NR) {
        float4 o4={o0,o1,o2,o3};
        *(float4*)dp = o4;
    } else {
        if (n0+nc   < NR) dp[0]=o0;
        if (n0+nc+1 < NR) dp[1]=o1;
        if (n0+nc+2 < NR) dp[2]=o2;
        if (n0+nc+3 < NR) dp[3]=o3;
    }
}

// Distributed LayerNorm: thread t owns (r=t>>7, d=t&127).
__device__ __forceinline__ void ln512(float hv,
    const float* __restrict__ lw, const float* __restrict__ lb,
    float* hnS, float* red, int t)
{
    int r = t >> 7, d = t & 127;
    float s = hv, s2 = hv*hv;
    #pragma unroll
    for (int o=1;o<64;o<<=1){ s += __shfl_xor(s,o); s2 += __shfl_xor(s2,o); }
    int wid = t >> 6;
    if ((t & 63) == 0){ red[wid] = s; red[8+wid] = s2; }
    __syncthreads();
    float S  = red[2*r]   + red[2*r+1];
    float S2 = red[8+2*r] + red[8+2*r+1];
    float mu = S*(1.f/128.f), var = S2*(1.f/128.f)-mu*mu;
    float rr = rsqrtf(var+EPSF);
    hnS[r*128+d] = (hv-mu)*rr*lw[d]+lb[d];
    __syncthreads();
}

#define FMA4(Wv, av) \
    acc[r].x=fmaf(av,(Wv).x,acc[r].x); acc[r].y=fmaf(av,(Wv).y,acc[r].y); \
    acc[r].z=fmaf(av,(Wv).z,acc[r].z); acc[r].w=fmaf(av,(Wv).w,acc[r].w);
#define MAX4(Wv, av) \
    acc[r].x=fmaxf(acc[r].x,av+(Wv).x); acc[r].y=fmaxf(acc[r].y,av+(Wv).y); \
    acc[r].z=fmaxf(acc[r].z,av+(Wv).z); acc[r].w=fmaxf(acc[r].w,av+(Wv).w);

// QKV + gate, double-buffered batch-8 weight loads.
__device__ __forceinline__ void qkvT512(const float* hnS, float* pacc, int r0, int t,
    const float* __restrict__ wqT, const float* __restrict__ bq,
    const float* __restrict__ wkT, const float* __restrict__ bk,
    const float* __restrict__ wvT, const float* __restrict__ bv,
    const float* __restrict__ gwT, const float* __restrict__ gb,
    float* __restrict__ Q, float* __restrict__ Kg, float* __restrict__ V,
    float* __restrict__ g)
{
    if (t < 384) {
        int mat = t >> 7, q4i = t & 31, ks = (t >> 5) & 3;
        const float* wT = (mat==0) ? wqT : (mat==1) ? wkT : wvT;
        const float4* w4 = (const float4*)wT + q4i;
        int kbase = ks*32;
        float4 wA[8], wB[8];
        #pragma unroll
        for (int j=0;j<8;++j) wA[j]=w4[(kbase+j)*32];
        float4 acc[4];
        if (mat < 2) {
            #pragma unroll
            for (int r=0;r<4;++r){ acc[r].x=acc[r].y=acc[r].z=acc[r].w=-1e30f; }
            #pragma unroll
            for (int pp=0;pp<2;++pp){
                int k0 = kbase + pp*16;
                #pragma unroll
                for (int j=0;j<8;++j) wB[j]=w4[(k0+8+j)*32];
                #pragma unroll
                for (int j=0;j<8;++j){
                    #pragma unroll
                    for (int r=0;r<4;++r){ float av=hnS[r*128+k0+j]; MAX4(wA[j],av) }
                }
                if (pp<1){
                    #pragma unroll
                    for (int j=0;j<8;++j) wA[j]=w4[(k0+16+j)*32];
                }
                #pragma unroll
                for (int j=0;j<8;++j){
                    #pragma unroll
                    for (int r=0;r<4;++r){ float av=hnS[r*128+k0+8+j]; MAX4(wB[j],av) }
                }
            }
        } else {
            #pragma unroll
            for (int r=0;r<4;++r){ acc[r].x=acc[r].y=acc[r].z=acc[r].w=0.f; }
            #pragma unroll
            for (int pp=0;pp<2;++pp){
                int k0 = kbase + pp*16;
                #pragma unroll
                for (int j=0;j<8;++j) wB[j]=w4[(k0+8+j)*32];
                #pragma unroll
                for (int j=0;j<8;++j){
                    #pragma unroll
                    for (int r=0;r<4;++r){ float av=hnS[r*128+k0+j]; FMA4(wA[j],av) }
                }
                if (pp<1){
                    #pragma unroll
                    for (int j=0;j<8;++j) wA[j]=w4[(k0+16+j)*32];
                }
                #pragma unroll
                for (int j=0;j<8;++j){
                    #pragma unroll
                    for (int r=0;r<4;++r){ float av=hnS[r*128+k0+8+j]; FMA4(wB[j],av) }
                }
            }
        }
        #pragma unroll
        for (int r=0;r<4;++r)
            *(float4*)(pacc + mat*2048 + ks*512 + r*128 + q4i*4) = acc[r];
    } else {
        int u = t & 127, r = u>>5, hh=(u>>2)&7, ks=u&3;
        const float* a = hnS + r*128;
        float acc = 0.f;
        #pragma unroll
        for (int kb=0;kb<2;++kb){
            float wv16[16];
            #pragma unroll
            for (int j=0;j<16;++j) wv16[j]=gwT[(ks*32+kb*16+j)*8+hh];
            #pragma unroll
            for (int j=0;j<16;++j) acc = fmaf(a[ks*32+kb*16+j], wv16[j], acc);
        }
        acc += __shfl_xor(acc,1);
        acc += __shfl_xor(acc,2);
        if (ks==0) g[(r0+r)*8+hh] = sigm(acc + gb[hh]);
    }
    __syncthreads();
    if (t < 384) {
        int mat=t>>7, d=t&127;
        float* dst = (mat==0) ? Q : (mat==1) ? Kg : V;
        const float* bias = (mat==0) ? bq : (mat==1) ? bk : bv;
        #pragma unroll
        for (int r=0;r<4;++r){
            float p0 = pacc[mat*2048 + 0*512 + r*128 + d];
            float p1 = pacc[mat*2048 + 1*512 + r*128 + d];
            float p2 = pacc[mat*2048 + 2*512 + r*128 + d];
            float p3 = pacc[mat*2048 + 3*512 + r*128 + d];
            float s = (mat < 2) ? fmaxf(fmaxf(p0,p1), fmaxf(p2,p3))
                                : (p0 + p1 + p2 + p3);
            dst[(size_t)(r0+r)*128 + d] = s + bias[d];
        }
    }
}

// ---------------------------------------------------------------------------
// K1: patchify + patch embed + BN + LN1 + QKVG(layer0).  197 blocks x 512
// ---------------------------------------------------------------------------
__global__ __launch_bounds__(512, 2) void k_p1(
    const float* __restrict__ x, const float* __restrict__ pwT, const float* __restrict__ pb,
    const float* __restrict__ clsT, const float* __restrict__ pos,
    const float* __restrict__ bng, const float* __restrict__ bnb,
    const float* __restrict__ bnm, const float* __restrict__ bnr,
    const float* __restrict__ n1w, const float* __restrict__ n1b,
    const float* __restrict__ wqT, const float* __restrict__ bq,
    const float* __restrict__ wkT, const float* __restrict__ bk,
    const float* __restrict__ wvT, const float* __restrict__ bv,
    const float* __restrict__ gwT, const float* __restrict__ gb,
    float* __restrict__ h, float* __restrict__ Q, float* __restrict__ Kg,
    float* __restrict__ V, float* __restrict__ g)
{
    __shared__ __align__(16) float xp[4*768];
    __shared__ __align__(16) float pacc[8192];
    __shared__ __align__(16) float hnS[512];
    __shared__ float red[16];
    int t = threadIdx.x, r0 = blockIdx.x * 4;

    // prefetch first patch-GEMM weight batch before staging barrier
    int q4i = t & 31, ks = t >> 5;
    const float4* w4 = (const float4*)pwT + q4i;
    int kbase = ks*48;
    float4 wA[8], wB[8];
    #pragma unroll
    for (int j=0;j<8;++j) wA[j] = w4[(kbase+j)*32];

    // stage patches (coalesced)
    #pragma unroll
    for (int r=0;r<4;++r){
        int row=r0+r, b=row/197, l=row-b*197;
        if (l>0){
            int patch=l-1, ph=patch/14, pc=patch-ph*14;
            const float* xb = x + (size_t)b*150528 + ph*3584 + pc*16;
            for (int i=t;i<768;i+=512){
                int c=i>>8, rr=(i>>4)&15, cc=i&15;
                xp[r*768+i] = xb[c*50176 + rr*224 + cc];
            }
        }
    }
    __syncthreads();

    // patch GEMM: 6 rounds of 8, A/B double-buffered
    {
        float4 acc[4];
        #pragma unroll
        for (int r=0;r<4;++r){ acc[r].x=acc[r].y=acc[r].z=acc[r].w=0.f; }
        #pragma unroll
        for (int pp=0;pp<3;++pp){
            int k0 = kbase + pp*16;
            #pragma unroll
            for (int j=0;j<8;++j) wB[j]=w4[(k0+8+j)*32];
            #pragma unroll
            for (int j=0;j<8;++j){
                #pragma unroll
                for (int r=0;r<4;++r){ float av=xp[r*768+k0+j]; FMA4(wA[j],av) }
            }
            if (pp<2){
                #pragma unroll
                for (int j=0;j<8;++j) wA[j]=w4[(k0+16+j)*32];
            }
            #pragma unroll
            for (int j=0;j<8;++j){
                #pragma unroll
                for (int r=0;r<4;++r){ float av=xp[r*768+k0+8+j]; FMA4(wB[j],av) }
            }
        }
        #pragma unroll
        for (int r=0;r<4;++r)
            *(float4*)(pacc + (ks*4+r)*128 + q4i*4) = acc[r];
    }
    __syncthreads();

    float hres;
    {
        int r=t>>7, d=t&127;
        int row=r0+r, l=row%197;
        float s = 0.f;
        #pragma unroll
        for (int k2=0;k2<16;++k2) s += pacc[(k2*4+r)*128+d];
        float v = (l==0) ? clsT[d] : (s + pb[d]);
        v += pos[l*128+d];
        v = bng[d]*((v-bnm[d])/(bnr[d]+EPSF))+bnb[d];
        hres=v;
        h[row*128+d]=v;
    }
    __syncthreads();
    ln512(hres, n1w, n1b, hnS, red, t);
    qkvT512(hnS, pacc, r0, t, wqT,bq,wkT,bk,wvT,bv,gwT,gb, Q,Kg,V,g);
}

// ---------------------------------------------------------------------------
// K2: fused attention (unchanged).  224 blocks x 256
// ---------------------------------------------------------------------------
__global__ __launch_bounds__(256) void k_attn(
    const float* __restrict__ Qd, const float* __restrict__ Kd,
    const float* __restrict__ Vd, const float* __restrict__ gd,
    const float* __restrict__ tempL, float* __restrict__ ao)
{
    __shared__ __align__(16) float Ks[197*20];
    __shared__ __align__(16) float Vs[197*20];
    int bid = blockIdx.x, t = threadIdx.x;
    int qc = bid % 7, bh = bid / 7, hh = bh & 7, b = bh >> 3;
    size_t base = (size_t)(b*197)*128 + hh*16;

    {
        const float4* ksrc=(const float4*)(Kd+base);
        const float4* vsrc=(const float4*)(Vd+base);
        float4* kdst=(float4*)Ks; float4* vdst=(float4*)Vs;
        for (int idx=t; idx<788; idx+=256){
            int l=idx>>2, jj=idx&3;
            kdst[l*5+jj]=ksrc[l*32+jj];
            vdst[l*5+jj]=vsrc[l*32+jj];
        }
    }
    __syncthreads();

    int q = qc*32 + (t>>3), j8 = t&7;
    if (q >= 197) return;

    float Qr[16];
    {
        const float4* qp=(const float4*)(Qd+base+(size_t)q*128);
        #pragma unroll
        for (int u=0;u<4;++u){
            float4 v=qp[u];
            Qr[4*u]=v.x; Qr[4*u+1]=v.y; Qr[4*u+2]=v.z; Qr[4*u+3]=v.w;
        }
    }
    float gq = gd[(b*197+q)*8+hh];
    float it = 0.25f / tempL[hh];
    float gg = gq*it, cg = (1.f-gq)*it;

    float m=-1e30f, lsum=0.f, o[16];
    #pragma unroll
    for (int j=0;j<16;++j) o[j]=0.f;

    for (int k=j8;k<197;k+=8){
        const float4* kr4=(const float4*)(Ks+k*20);
        float4 kv0=kr4[0], kv1=kr4[1], kv2=kr4[2], kv3=kr4[3];
        float kr[16] = {kv0.x,kv0.y,kv0.z,kv0.w, kv1.x,kv1.y,kv1.z,kv1.w,
                        kv2.x,kv2.y,kv2.z,kv2.w, kv3.x,kv3.y,kv3.z,kv3.w};
        float cs=0.f, ts=-1e30f;
        #pragma unroll
        for (int j=0;j<16;++j){
            cs=fmaf(Qr[j],kr[j],cs);
            ts=fmaxf(ts,Qr[j]+kr[j]);
        }
        float sc=fmaf(gg,ts,cg*cs);
        if (sc>m){
            float c=__expf(m-sc);
            lsum*=c;
            #pragma unroll
            for (int j=0;j<16;++j) o[j]*=c;
            m=sc;
        }
        float p=__expf(sc-m);
        lsum+=p;
        const float4* vr4=(const float4*)(Vs+k*20);
        float4 vv0=vr4[0], vv1=vr4[1], vv2=vr4[2], vv3=vr4[3];
        float vr[16] = {vv0.x,vv0.y,vv0.z,vv0.w, vv1.x,vv1.y,vv1.z,vv1.w,
                        vv2.x,vv2.y,vv2.z,vv2.w, vv3.x,vv3.y,vv3.z,vv3.w};
        #pragma unroll
        for (int j=0;j<16;++j) o[j]=fmaf(p,vr[j],o[j]);
    }

    #pragma unroll
    for (int mask=1;mask<8;mask<<=1){
        float mo=__shfl_xor(m,mask), lo=__shfl_xor(lsum,mask);
        float mn=fmaxf(m,mo);
        float ea=__expf(m-mn), eb=__expf(mo-mn);
        lsum=lsum*ea+lo*eb;
        #pragma unroll
        for (int j=0;j<16;++j){
            float oo=__shfl_xor(o[j],mask);
            o[j]=o[j]*ea+oo*eb;
        }
        m=mn;
    }

    if (j8==0){
        float inv=1.f/lsum;
        float* orow=ao+base+(size_t)q*128;
        #pragma unroll
        for (int j=0;j<16;++j) orow[j]=o[j]*inv;
    }
}

// ---------------------------------------------------------------------------
// K3: oproj+res+LN2 + FFN + dproj+res + next-LN + (QKVG | head)
// 197 blocks x 512; double-buffered weight streams everywhere.
// ---------------------------------------------------------------------------
template <int FINAL>
__global__ __launch_bounds__(512, 2) void k_p34(
    const float* __restrict__ ao, float* __restrict__ h,
    const float* __restrict__ woT, const float* __restrict__ bo,
    const float* __restrict__ n2w, const float* __restrict__ n2b,
    const float* __restrict__ tuT, const float* __restrict__ tub,
    const float* __restrict__ laA, const float* __restrict__ laC,
    const float* __restrict__ lgG,
    const float* __restrict__ cuT, const float* __restrict__ cub,
    const float* __restrict__ fgT, const float* __restrict__ fgb,
    const float* __restrict__ dnT, const float* __restrict__ dnb,
    const float* __restrict__ nlw, const float* __restrict__ nlb,
    const float* __restrict__ wqT, const float* __restrict__ bq,
    const float* __restrict__ wkT, const float* __restrict__ bk,
    const float* __restrict__ wvT, const float* __restrict__ bv,
    const float* __restrict__ gwT, const float* __restrict__ gb,
    float* __restrict__ Q, float* __restrict__ Kg, float* __restrict__ V,
    float* __restrict__ g,
    const float* __restrict__ hdT, const float* __restrict__ hdb,
    float* __restrict__ out)
{
    __shared__ __align__(16) float aoS[512];
    __shared__ __align__(16) float pacc[8192];
    __shared__ __align__(16) float hnS[512];
    __shared__ __align__(16) float zP[6144];
    __shared__ __align__(16) float fusedS[1024];
    __shared__ float red[16];
    int t = threadIdx.x, r0 = blockIdx.x * 4;

    // preload oproj's weight batch before the staging barrier
    int q4i=t&31, ks=t>>5;
    const float4* w4o=(const float4*)woT + q4i;
    float4 wo8[8];
    #pragma unroll
    for (int j=0;j<8;++j) wo8[j]=w4o[(ks*8+j)*32];

    aoS[t] = ao[(size_t)r0*128 + t];
    __syncthreads();

    // oproj: 1 round (weights already in registers)
    {
        float4 acc[4];
        #pragma unroll
        for (int r=0;r<4;++r){ acc[r].x=acc[r].y=acc[r].z=acc[r].w=0.f; }
        #pragma unroll
        for (int j=0;j<8;++j){
            #pragma unroll
            for (int r=0;r<4;++r){ float av=aoS[r*128 + ks*8+j]; FMA4(wo8[j],av) }
        }
        #pragma unroll
        for (int r=0;r<4;++r)
            *(float4*)(pacc + (ks*4+r)*128 + q4i*4) = acc[r];
    }
    __syncthreads();

    float hres;
    {
        int r=t>>7, d=t&127;
        float s=0.f;
        #pragma unroll
        for (int k2=0;k2<16;++k2) s += pacc[(k2*4+r)*128+d];
        hres = h[(size_t)(r0+r)*128+d] + s + bo[d];
    }
    __syncthreads();
    ln512(hres, n2w, n2b, hnS, red, t);

    // FFN: 6 groups of 64; 8 rounds of 8, A/B double-buffered
    {
        int gidx=t>>6, fq=t&63;
        if (gidx < 6) {
            int mat=gidx>>1, ks2=gidx&1;
            const float* wT = (mat==0)? tuT : (mat==1)? cuT : fgT;
            const float4* w4=(const float4*)wT + fq;
            int kbase = ks2*64;
            float4 wA[8], wB[8];
            #pragma unroll
            for (int j=0;j<8;++j) wA[j]=w4[(kbase+j)*64];
            float4 acc[4];
            if (mat==0){
                #pragma unroll
                for (int r=0;r<4;++r){ acc[r].x=acc[r].y=acc[r].z=acc[r].w=-1e30f; }
                #pragma unroll
                for (int pp=0;pp<4;++pp){
                    int k0 = kbase + pp*16;
                    #pragma unroll
                    for (int j=0;j<8;++j) wB[j]=w4[(k0+8+j)*64];
                    #pragma unroll
                    for (int j=0;j<8;++j){
                        #pragma unroll
                        for (int r=0;r<4;++r){ float av=hnS[r*128+k0+j]; MAX4(wA[j],av) }
                    }
                    if (pp<3){
                        #pragma unroll
                        for (int j=0;j<8;++j) wA[j]=w4[(k0+16+j)*64];
                    }
                    #pragma unroll
                    for (int j=0;j<8;++j){
                        #pragma unroll
                        for (int r=0;r<4;++r){ float av=hnS[r*128+k0+8+j]; MAX4(wB[j],av) }
                    }
                }
            } else {
                #pragma unroll
                for (int r=0;r<4;++r){ acc[r].x=acc[r].y=acc[r].z=acc[r].w=0.f; }
                #pragma unroll
                for (int pp=0;pp<4;++pp){
                    int k0 = kbase + pp*16;
                    #pragma unroll
                    for (int j=0;j<8;++j) wB[j]=w4[(k0+8+j)*64];
                    #pragma unroll
                    for (int j=0;j<8;++j){
                        #pragma unroll
                        for (int r=0;r<4;++r){ float av=hnS[r*128+k0+j]; FMA4(wA[j],av) }
                    }
                    if (pp<3){
                        #pragma unroll
                        for (int j=0;j<8;++j) wA[j]=w4[(k0+16+j)*64];
                    }
                    #pragma unroll
                    for (int j=0;j<8;++j){
                        #pragma unroll
                        for (int r=0;r<4;++r){ float av=hnS[r*128+k0+8+j]; FMA4(wB[j],av) }
                    }
                }
            }
            #pragma unroll
            for (int r=0;r<4;++r)
                *(float4*)(zP + mat*2048 + ks2*1024 + r*256 + fq*4) = acc[r];
        }
    }
    __syncthreads();

    // FFN epilogue: 1024 (r,f) slots over 512 threads
    #pragma unroll
    for (int s2=0;s2<2;++s2){
        int slot = t + s2*512;
        int r = slot>>8, f = slot&255;
        float z  = fmaxf(zP[r*256+f],        zP[1024+r*256+f]) + tub[f];
        float xc = zP[2048+r*256+f] + zP[3072+r*256+f] + cub[f];
        float gv = zP[4096+r*256+f] + zP[5120+r*256+f] + fgb[f];
        float gl = sigm(lgG[f]);
        float mx=-1e30f, mn=1e30f;
        #pragma unroll
        for (int p=0;p<8;++p){
            float zp=fmaf(z, laA[p*256+f], laC[p*256+f]);
            mx=fmaxf(mx,zp); mn=fminf(mn,zp);
        }
        float trop=gl*mx+(1.f-gl)*mn;
        float cla=0.5f*xc*(1.f+erff(xc*0.70710678118654752f));
        float gf=sigm(gv);
        fusedS[r*256+f]=gf*trop+(1.f-gf)*cla;
    }
    __syncthreads();

    // dproj: 2 rounds of 8
    {
        const float4* w4=(const float4*)dnT + q4i;
        int kbase = ks*16;
        float4 wA[8], wB[8];
        #pragma unroll
        for (int j=0;j<8;++j) wA[j]=w4[(kbase+j)*32];
        #pragma unroll
        for (int j=0;j<8;++j) wB[j]=w4[(kbase+8+j)*32];
        float4 acc[4];
        #pragma unroll
        for (int r=0;r<4;++r){ acc[r].x=acc[r].y=acc[r].z=acc[r].w=0.f; }
        #pragma unroll
        for (int j=0;j<8;++j){
            #pragma unroll
            for (int r=0;r<4;++r){ float av=fusedS[r*256+kbase+j]; FMA4(wA[j],av) }
        }
        #pragma unroll
        for (int j=0;j<8;++j){
            #pragma unroll
            for (int r=0;r<4;++r){ float av=fusedS[r*256+kbase+8+j]; FMA4(wB[j],av) }
        }
        __syncthreads();
        #pragma unroll
        for (int r=0;r<4;++r)
            *(float4*)(pacc + (ks*4+r)*128 + q4i*4) = acc[r];
    }
    __syncthreads();
    {
        int r=t>>7, d=t&127;
        float s=0.f;
        #pragma unroll
        for (int k2=0;k2<16;++k2) s += pacc[(k2*4+r)*128+d];
        hres += s + dnb[d];
        if (!FINAL) h[(size_t)(r0+r)*128+d]=hres;
    }
    __syncthreads();
    ln512(hres, nlw, nlb, hnS, red, t);

    if (!FINAL) {
        qkvT512(hnS, pacc, r0, t, wqT,bq,wkT,bk,wvT,bv,gwT,gb, Q,Kg,V,g);
    } else {
        int crow=-1, cb2=0;
        #pragma unroll
        for (int r=0;r<4;++r){
            int row=r0+r;
            if (row==0 || row==197 || row==394 || row==591){ crow=r; cb2=row/197; }
        }
        if (crow>=0 && t<500){
            const float2* w2=(const float2*)hdT + t;
            const float* a = hnS + crow*128;
            float acc0=hdb[2*t], acc1=hdb[2*t+1];
            float2 wA[8], wB[8];
            #pragma unroll
            for (int j=0;j<8;++j) wA[j]=w2[j*500];
            #pragma unroll
            for (int pp=0;pp<8;++pp){
                int k0 = pp*16;
                #pragma unroll
                for (int j=0;j<8;++j) wB[j]=w2[(k0+8+j)*500];
                #pragma unroll
                for (int j=0;j<8;++j){
                    float av=a[k0+j];
                    acc0=fmaf(av,wA[j].x,acc0); acc1=fmaf(av,wA[j].y,acc1);
                }
                if (pp<7){
                    #pragma unroll
                    for (int j=0;j<8;++j) wA[j]=w2[(k0+16+j)*500];
                }
                #pragma unroll
                for (int j=0;j<8;++j){
                    float av=a[k0+8+j];
                    acc0=fmaf(av,wB[j].x,acc0); acc1=fmaf(av,wB[j].y,acc1);
                }
            }
            out[cb2*1000+2*t]=acc0;
            out[cb2*1000+2*t+1]=acc1;
        }
    }
}

// ---------------------------------------------------------------------------
extern "C" void kernel_launch(void* const* d_in, const int* in_sizes, int n_in,
                              void* d_out, int out_size, void* d_ws, size_t ws_size,
                              hipStream_t stream)
{
    const float* x        = (const float*)d_in[0];
    const float* patch_w  = (const float*)d_in[1];
    const float* patch_b  = (const float*)d_in[2];
    const float* cls_tok  = (const float*)d_in[3];
    const float* pos_emb  = (const float*)d_in[4];
    const float* bn_gamma = (const float*)d_in[5];
    const float* bn_beta  = (const float*)d_in[6];
    const float* bn_rmax  = (const float*)d_in[7];
    const float* bn_rrng  = (const float*)d_in[8];
    const float* n1_w     = (const float*)d_in[9];
    const float* n1_b     = (const float*)d_in[10];
    const float* n2_w     = (const float*)d_in[11];
    const float* n2_b     = (const float*)d_in[12];
    const float* wq       = (const float*)d_in[13];
    const float* bq       = (const float*)d_in[14];
    const float* wk       = (const float*)d_in[15];
    const float* bk       = (const float*)d_in[16];
    const float* wv       = (const float*)d_in[17];
    const float* bv       = (const float*)d_in[18];
    const float* wo       = (const float*)d_in[19];
    const float* bo       = (const float*)d_in[20];
    const float* gate_w   = (const float*)d_in[21];
    const float* gate_b   = (const float*)d_in[22];
    const float* temp     = (const float*)d_in[23];
    const float* tu_w     = (const float*)d_in[24];
    const float* tu_b     = (const float*)d_in[25];
    const float* lf_a     = (const float*)d_in[26];
    const float* lf_c     = (const float*)d_in[27];
    const float* lf_gate  = (const float*)d_in[28];
    const float* cu_w     = (const float*)d_in[29];
    const float* cu_b     = (const float*)d_in[30];
    const float* fg_w     = (const float*)d_in[31];
    const float* fg_b     = (const float*)d_in[32];
    const float* dn_w     = (const float*)d_in[33];
    const float* dn_b     = (const float*)d_in[34];
    const float* fn_w     = (const float*)d_in[35];
    const float* fn_b     = (const float*)d_in[36];
    const float* head_w   = (const float*)d_in[37];
    const float* head_b   = (const float*)d_in[38];

    float* ws = (float*)d_ws;
    float* h   = ws + WS_H;
    float* Q   = ws + WS_Q;
    float* Kb  = ws + WS_K;
    float* V   = ws + WS_V;
    float* g   = ws + WS_G;
    float* ao  = ws + WS_AO;
    float* out = (float*)d_out;

    k_tr<<<609, 256, 0, stream>>>(patch_w, wq, wk, wv, wo, gate_w,
                                  tu_w, cu_w, fg_w, dn_w, head_w, ws);

    k_p1<<<197, 512, 0, stream>>>(x, ws+WS_PWT, patch_b, cls_tok, pos_emb,
                                  bn_gamma, bn_beta, bn_rmax, bn_rrng,
                                  n1_w, n1_b,
                                  ws+WS_WQT, bq, ws+WS_WKT, bk, ws+WS_WVT, bv,
                                  ws+WS_GWT, gate_b,
                                  h, Q, Kb, V, g);

    k_attn<<<224, 256, 0, stream>>>(Q, Kb, V, g, temp, ao);

    k_p34<0><<<197, 512, 0, stream>>>(ao, h,
        ws+WS_WOT, bo, n2_w, n2_b,
        ws+WS_TUT, tu_b, lf_a, lf_c, lf_gate,
        ws+WS_CUT, cu_b, ws+WS_FGT, fg_b, ws+WS_DNT, dn_b,
        n1_w + 128, n1_b + 128,
        ws+WS_WQT+16384, bq + 128, ws+WS_WKT+16384, bk + 128,
        ws+WS_WVT+16384, bv + 128, ws+WS_GWT+1024, gate_b + 8,
        Q, Kb, V, g, nullptr, nullptr, nullptr);

    k_attn<<<224, 256, 0, stream>>>(Q, Kb, V, g, temp + 8, ao);

    k_p34<1><<<197, 512, 0, stream>>>(ao, h,
        ws+WS_WOT+16384, bo + 128, n2_w + 128, n2_b + 128,
        ws+WS_TUT+32768, tu_b + 256, lf_a + 2048, lf_c + 2048, lf_gate + 256,
        ws+WS_CUT+32768, cu_b + 256, ws+WS_FGT+32768, fg_b + 256,
        ws+WS_DNT+32768, dn_b + 128,
        fn_w, fn_b,
        nullptr, nullptr, nullptr, nullptr, nullptr, nullptr, nullptr, nullptr,
        Q, Kb, V, g, ws+WS_HDT, head_b, out);
}